// Round 23
// baseline (156.903 us; speedup 1.0000x reference)
//
#include <hip/hip_runtime.h>
#include <hip/hip_bf16.h>

#define DELTA 0.05f

typedef __attribute__((ext_vector_type(8))) short short8;
typedef __attribute__((ext_vector_type(4))) float f32x4;
typedef __attribute__((ext_vector_type(4))) int int4v;
typedef __attribute__((ext_vector_type(8))) int int8v;
typedef __attribute__((ext_vector_type(16))) float f32x16;

__device__ __forceinline__ unsigned short tern_bits(float v) {
    return v > DELTA ? 0x3F80u : (v < -DELTA ? 0xBF80u : 0u);
}

__device__ __forceinline__ short f32_to_bf16_bits(float v) {
    __hip_bfloat16 h = __float2bfloat16(v);
    unsigned short bits;
    __builtin_memcpy(&bits, &h, 2);
    return (short)bits;
}

// e2m1 nibble: nearest of {0,±0.5,±1,±1.5,±2,±3,±4,±6}; exact for {0,±1}
__device__ __forceinline__ unsigned int nib_e2m1(float v) {
    float a = fabsf(v);
    unsigned int s = v < 0.0f ? 8u : 0u;
    unsigned int m;
    if (a < 0.25f) return 0u;
    else if (a < 0.75f) m = 1u;
    else if (a < 1.25f) m = 2u;
    else if (a < 1.75f) m = 3u;
    else if (a < 2.5f)  m = 4u;
    else if (a < 3.5f)  m = 5u;
    else if (a < 5.0f)  m = 6u;
    else                m = 7u;
    return s | m;
}

// ---- fused quantize to PACKED fp4 (2 elems/byte; verified absmax 0 in r20) --
__global__ void quant_ab4_kernel(const float* __restrict__ x,
                                 const float* __restrict__ w,
                                 const float* __restrict__ ap,
                                 const float* __restrict__ an,
                                 unsigned char* __restrict__ aq,
                                 unsigned char* __restrict__ wq,
                                 int K, long totalA, long totalW, int ABLK) {
    if ((int)blockIdx.x < ABLK) {
        long idx = ((long)blockIdx.x * blockDim.x + threadIdx.x) * 32;
        long stride = (long)ABLK * blockDim.x * 32;
        for (; idx < totalA; idx += stride) {
            const float4* p = reinterpret_cast<const float4*>(x + idx);
            union { unsigned char c[16]; int4v v; } r;
#pragma unroll
            for (int q = 0; q < 8; ++q) {
                float4 f = p[q];
                unsigned int lo0 = f.x > DELTA ? 2u : (f.x < -DELTA ? 10u : 0u);
                unsigned int hi0 = f.y > DELTA ? 2u : (f.y < -DELTA ? 10u : 0u);
                unsigned int lo1 = f.z > DELTA ? 2u : (f.z < -DELTA ? 10u : 0u);
                unsigned int hi1 = f.w > DELTA ? 2u : (f.w < -DELTA ? 10u : 0u);
                r.c[q * 2 + 0] = (unsigned char)(lo0 | (hi0 << 4));
                r.c[q * 2 + 1] = (unsigned char)(lo1 | (hi1 << 4));
            }
            *reinterpret_cast<int4v*>(aq + idx / 2) = r.v;
        }
    } else {
        int wb = (int)blockIdx.x - ABLK;
        int nwb = (int)gridDim.x - ABLK;
        long idx = ((long)wb * blockDim.x + threadIdx.x) * 32;
        long stride = (long)nwb * blockDim.x * 32;
        for (; idx < totalW; idx += stride) {
            int n = (int)(idx / K);
            float pv = ap[n], nv = -an[n];
            const float4* p = reinterpret_cast<const float4*>(w + idx);
            union { unsigned char c[16]; int4v v; } r;
#pragma unroll
            for (int q = 0; q < 8; ++q) {
                float4 f = p[q];
                float e0 = f.x > DELTA ? pv : (f.x < -DELTA ? nv : 0.0f);
                float e1 = f.y > DELTA ? pv : (f.y < -DELTA ? nv : 0.0f);
                float e2 = f.z > DELTA ? pv : (f.z < -DELTA ? nv : 0.0f);
                float e3 = f.w > DELTA ? pv : (f.w < -DELTA ? nv : 0.0f);
                r.c[q * 2 + 0] = (unsigned char)(nib_e2m1(e0) | (nib_e2m1(e1) << 4));
                r.c[q * 2 + 1] = (unsigned char)(nib_e2m1(e2) | (nib_e2m1(e3) << 4));
            }
            *reinterpret_cast<int4v*>(wq + idx / 2) = r.v;
        }
    }
}

// ====== 256x128 fp4 GEMM (r22 keeper + waves_per_eu(2,2) regalloc unlock) ====
// r22 (GEMM 103.5us, absmax 0) spilled ~8 regs/lane (VGPR_Count 128 at the
// occupancy quantum while demand ~160; WRITE_SIZE 151.5MB vs C=134MB): LDS
// (96KB) already limits to 1 block/CU = 2 waves/SIMD, so allocating up to
// 256 regs is free, but __launch_bounds__ only sets a MINIMUM waves/EU and
// the allocator chased 4 waves/EU. FIX: amdgpu_waves_per_eu(2,2) pins the
// ceiling so regalloc can use the full 256. Kernel body identical to r22.
__global__ __attribute__((amdgpu_flat_work_group_size(512, 512),
                          amdgpu_waves_per_eu(2, 2))) void gemm4p(
    const unsigned char* __restrict__ A, const unsigned char* __restrict__ B,
    const float* __restrict__ bias, float* __restrict__ C,
    int M, int N, int Kb) {
    __shared__ unsigned char As[2 * 256 * 128];   // 64 KB (2 buf x 32KB)
    __shared__ unsigned char Bs[2 * 128 * 128];   // 32 KB (2 buf x 16KB)

    const int tid = threadIdx.x;
    const int wid = tid >> 6;
    const int ln  = tid & 63;
    const int wr  = wid >> 2;   // 0..1 (128-row half)
    const int wc  = wid & 3;    // 0..3 (32-col group)

    // --- XCD-chunked swizzle (bijective: gridDim.y % 8 == 0)
    int bx = blockIdx.x, by = blockIdx.y;
    if ((gridDim.y & 7) == 0) {
        const int nbx = gridDim.x;
        const int rpx = gridDim.y >> 3;
        int bid = by * nbx + bx;
        int xcd = bid & 7;
        int off = bid >> 3;
        by = xcd * rpx + (off % rpx);
        bx = off / rpx;
    }
    const int brow = by * 256;
    const int bcol = bx * 128;

    const int NT   = Kb >> 7;   // 128-byte K-tiles (256 fp4 elems)
    const int STOT = NT * 3;    // units per tile: {B, A.h0, A.h1}, 16KB each

    // staging geometry: unit = 128 rows x 128B = 16KB; wave does 2 chunks of
    // 8 rows x 128B (1KB) at chunk0, chunk0+1.
    const int srow   = ln >> 3;
    const int scol   = ((ln & 7) ^ srow) * 16;  // inverse-swizzled source byte
    const int chunk0 = wid * 2;

    // ds_read geometry (bytes), 32x32 shape
    const int ln31 = ln & 31;
    const int swz  = (ln & 7) << 4;
    const int koff = (ln >> 5) << 4;

    f32x16 acc[4] = {};
    int8v bfrag[4];
    int s = 0;

    auto STAGE = [&](int si) {
        if (si >= STOT) return;
        int tile = si / 3, kind = si - tile * 3, buf = tile & 1;
        int kt = tile << 7;
        const unsigned char* g;
        int grow;
        unsigned char* lb;
        if (kind == 0) { g = B; grow = bcol; lb = Bs + buf * 16384; }
        else {
            g = A; grow = brow + (kind - 1) * 128;
            lb = As + buf * 32768 + (kind - 1) * 16384;
        }
#pragma unroll
        for (int j = 0; j < 2; ++j) {
            int c = chunk0 + j;
            const unsigned char* src =
                g + (size_t)(grow + c * 8 + srow) * Kb + kt + scol;
            __builtin_amdgcn_global_load_lds(
                (const __attribute__((address_space(1))) void*)src,
                (__attribute__((address_space(3))) void*)(lb + c * 1024),
                16, 0, 0);
        }
    };

// TAIL empty for non-gate phases; gate phases append vmcnt + barrier.
#define PHASE(BUF, Q, FIRST, DOSTG, TAIL)                                      \
    {                                                                          \
        const char* Ab = (const char*)As + (BUF) * 32768;                      \
        const char* Bb = (const char*)Bs + (BUF) * 16384;                      \
        int8v afrag[4];                                                        \
        {                                                                      \
            int r = wr * 128 + (Q) * 32 + ln31;                                \
            _Pragma("unroll")                                                  \
            for (int ks = 0; ks < 4; ++ks) {                                   \
                int4v t = *(const int4v*)(Ab + r * 128 +                       \
                                          ((ks * 32 + koff) ^ swz));           \
                afrag[ks] = (int8v){t[0], t[1], t[2], t[3], 0, 0, 0, 0};       \
            }                                                                  \
        }                                                                      \
        if (FIRST) {                                                           \
            int r = wc * 32 + ln31;                                            \
            _Pragma("unroll")                                                  \
            for (int ks = 0; ks < 4; ++ks) {                                   \
                int4v t = *(const int4v*)(Bb + r * 128 +                       \
                                          ((ks * 32 + koff) ^ swz));           \
                bfrag[ks] = (int8v){t[0], t[1], t[2], t[3], 0, 0, 0, 0};       \
            }                                                                  \
        }                                                                      \
        if (DOSTG) { STAGE(s); ++s; }                                          \
        __builtin_amdgcn_s_barrier();                                          \
        __builtin_amdgcn_s_setprio(1);                                         \
        _Pragma("unroll")                                                      \
        for (int ks = 0; ks < 4; ++ks)                                         \
            acc[(Q)] = __builtin_amdgcn_mfma_scale_f32_32x32x64_f8f6f4(        \
                afrag[ks], bfrag[ks], acc[(Q)],                                \
                4, 4, 0, 0x7F7F7F7F, 0, 0x7F7F7F7F);                           \
        __builtin_amdgcn_s_setprio(0);                                         \
        TAIL;                                                                  \
    }
#define GATE4 asm volatile("s_waitcnt vmcnt(4)" ::: "memory"); __builtin_amdgcn_s_barrier()
#define GATE0 asm volatile("s_waitcnt vmcnt(0)" ::: "memory"); __builtin_amdgcn_s_barrier()

    // prologue: T0{B,A0,A1} + T1{B,A0}; gate T0 (T1's 4 loads in flight)
    for (int i = 0; i < 5; ++i) { STAGE(s); ++s; }
    asm volatile("s_waitcnt vmcnt(4)" ::: "memory");
    __builtin_amdgcn_s_barrier();

    const int NI = (NT - 2) >> 1;
#pragma unroll 1
    for (int p = 0; p < NI; ++p) {
        PHASE(0, 0, true,  true,  (void)0)   // stage T+1.A1
        PHASE(0, 1, false, true,  (void)0)   // stage T+2.B (buf0.B read ph1 only)
        PHASE(0, 2, false, false, (void)0)
        PHASE(0, 3, false, true,  GATE4)     // stage T+2.A0 after A0's last reads
        PHASE(1, 0, true,  true,  (void)0)   // stage T+2.A1 (fenced by ph4 gate)
        PHASE(1, 1, false, true,  (void)0)   // stage T+3.B
        PHASE(1, 2, false, false, (void)0)
        PHASE(1, 3, false, true,  GATE4)     // stage T+3.A0
    }
    // epilogue: tiles NT-2 (buf0), NT-1 (buf1); one unit left (T_{NT-1}.A1)
    PHASE(0, 0, true,  true,  (void)0)
    PHASE(0, 1, false, false, (void)0)
    PHASE(0, 2, false, false, (void)0)
    PHASE(0, 3, false, false, GATE0)
    PHASE(1, 0, true,  false, (void)0)
    PHASE(1, 1, false, false, (void)0)
    PHASE(1, 2, false, false, (void)0)
    PHASE(1, 3, false, false, (void)0)
#undef PHASE
#undef GATE4
#undef GATE0

    // C write + bias. 32x32 D layout: col=lane&31, row=(q&3)+8*(q>>2)+4*(ln>>5)
#pragma unroll
    for (int Q = 0; Q < 4; ++Q) {
        int col = bcol + wc * 32 + ln31;
        float bv = bias[col];
        int rowbase = brow + wr * 128 + Q * 32 + ((ln >> 5) << 2);
#pragma unroll
        for (int q = 0; q < 16; ++q) {
            int row = rowbase + (q & 3) + ((q >> 2) << 3);
            C[(size_t)row * N + col] = acc[Q][q] + bv;
        }
    }
}

// ---------------- bf16 quant + fallback 128^2 GEMM (round-1, known-good) ----
__global__ void quant_a_kernel(const float* __restrict__ x,
                               unsigned short* __restrict__ out, long total) {
    long idx = ((long)blockIdx.x * blockDim.x + threadIdx.x) * 8;
    long stride = (long)gridDim.x * blockDim.x * 8;
    for (; idx < total; idx += stride) {
        const float4* p = reinterpret_cast<const float4*>(x + idx);
        float4 v0 = p[0], v1 = p[1];
        short8 r;
        r[0] = (short)tern_bits(v0.x); r[1] = (short)tern_bits(v0.y);
        r[2] = (short)tern_bits(v0.z); r[3] = (short)tern_bits(v0.w);
        r[4] = (short)tern_bits(v1.x); r[5] = (short)tern_bits(v1.y);
        r[6] = (short)tern_bits(v1.z); r[7] = (short)tern_bits(v1.w);
        *reinterpret_cast<short8*>(out + idx) = r;
    }
}

__global__ void quant_w_kernel(const float* __restrict__ w,
                               const float* __restrict__ ap,
                               const float* __restrict__ an,
                               unsigned short* __restrict__ out,
                               int K, long total) {
    long idx = ((long)blockIdx.x * blockDim.x + threadIdx.x) * 8;
    long stride = (long)gridDim.x * blockDim.x * 8;
    for (; idx < total; idx += stride) {
        int n = (int)(idx / K);
        float pv = ap[n], nv = -an[n];
        const float4* p = reinterpret_cast<const float4*>(w + idx);
        float4 v0 = p[0], v1 = p[1];
        float vals[8] = {v0.x, v0.y, v0.z, v0.w, v1.x, v1.y, v1.z, v1.w};
        short8 r;
#pragma unroll
        for (int e = 0; e < 8; ++e) {
            float v = vals[e];
            float ev = v > DELTA ? pv : (v < -DELTA ? nv : 0.0f);
            r[e] = f32_to_bf16_bits(ev);
        }
        *reinterpret_cast<short8*>(out + idx) = r;
    }
}

template <int MODE>
__global__ __launch_bounds__(256) void gemm_tern(
    const unsigned short* __restrict__ A, const unsigned short* __restrict__ B,
    const float* __restrict__ Xf, const float* __restrict__ Wf,
    const float* __restrict__ alpha_p, const float* __restrict__ alpha_n,
    const float* __restrict__ bias, float* __restrict__ C,
    int M, int N, int K) {
    __shared__ unsigned short As[128 * 32];
    __shared__ unsigned short Bs[128 * 32];

    const int tid = threadIdx.x;
    const int wv = tid >> 6;
    const int ln = tid & 63;
    const int brow = blockIdx.y * 128;
    const int bcol = blockIdx.x * 128;
    const int wr = wv >> 1;
    const int wc = wv & 1;

    f32x4 acc[4][4] = {};

    for (int kt = 0; kt < K; kt += 32) {
        if (MODE == 0) {
#pragma unroll
            for (int j = 0; j < 2; ++j) {
                int chunk = wv * 2 + j;
                int r = chunk * 16 + (ln >> 2);
                int kc = (ln & 3) * 8;
                const unsigned short* ga = A + (size_t)(brow + r) * K + kt + kc;
                const unsigned short* gb = B + (size_t)(bcol + r) * K + kt + kc;
                __builtin_amdgcn_global_load_lds(
                    (const __attribute__((address_space(1))) void*)ga,
                    (__attribute__((address_space(3))) void*)(As + chunk * 512),
                    16, 0, 0);
                __builtin_amdgcn_global_load_lds(
                    (const __attribute__((address_space(1))) void*)gb,
                    (__attribute__((address_space(3))) void*)(Bs + chunk * 512),
                    16, 0, 0);
            }
        } else {
#pragma unroll
            for (int j = 0; j < 2; ++j) {
                int chunk = wv * 2 + j;
                int r = chunk * 16 + (ln >> 2);
                int kc = (ln & 3) * 8;
                const float4* xa =
                    reinterpret_cast<const float4*>(Xf + (size_t)(brow + r) * K + kt + kc);
                float4 a0 = xa[0], a1 = xa[1];
                short8 ta;
                ta[0] = (short)tern_bits(a0.x); ta[1] = (short)tern_bits(a0.y);
                ta[2] = (short)tern_bits(a0.z); ta[3] = (short)tern_bits(a0.w);
                ta[4] = (short)tern_bits(a1.x); ta[5] = (short)tern_bits(a1.y);
                ta[6] = (short)tern_bits(a1.z); ta[7] = (short)tern_bits(a1.w);
                *reinterpret_cast<short8*>(As + chunk * 512 + ln * 8) = ta;

                int rn = bcol + r;
                float pv = alpha_p[rn], nv = -alpha_n[rn];
                const float4* wb =
                    reinterpret_cast<const float4*>(Wf + (size_t)rn * K + kt + kc);
                float4 b0 = wb[0], b1 = wb[1];
                float vals[8] = {b0.x, b0.y, b0.z, b0.w, b1.x, b1.y, b1.z, b1.w};
                short8 tb;
#pragma unroll
                for (int e = 0; e < 8; ++e) {
                    float v = vals[e];
                    float ev = v > DELTA ? pv : (v < -DELTA ? nv : 0.0f);
                    tb[e] = f32_to_bf16_bits(ev);
                }
                *reinterpret_cast<short8*>(Bs + chunk * 512 + ln * 8) = tb;
            }
        }
        __syncthreads();

        short8 af[4], bfr[4];
#pragma unroll
        for (int i = 0; i < 4; ++i) {
            int ra = wr * 64 + i * 16 + (ln & 15);
            af[i] = *reinterpret_cast<const short8*>(As + ra * 32 + (ln >> 4) * 8);
            int rb = wc * 64 + i * 16 + (ln & 15);
            bfr[i] = *reinterpret_cast<const short8*>(Bs + rb * 32 + (ln >> 4) * 8);
        }
#pragma unroll
        for (int i = 0; i < 4; ++i)
#pragma unroll
            for (int j = 0; j < 4; ++j)
                acc[i][j] = __builtin_amdgcn_mfma_f32_16x16x32_bf16(
                    af[i], bfr[j], acc[i][j], 0, 0, 0);
        __syncthreads();
    }

#pragma unroll
    for (int j = 0; j < 4; ++j) {
        int col = bcol + wc * 64 + j * 16 + (ln & 15);
        float bv = bias[col];
#pragma unroll
        for (int i = 0; i < 4; ++i) {
            int row0 = brow + wr * 64 + i * 16 + (ln >> 4) * 4;
#pragma unroll
            for (int q = 0; q < 4; ++q) {
                C[(size_t)(row0 + q) * N + col] = acc[i][j][q] + bv;
            }
        }
    }
}

extern "C" void kernel_launch(void* const* d_in, const int* in_sizes, int n_in,
                              void* d_out, int out_size, void* d_ws, size_t ws_size,
                              hipStream_t stream) {
    const float* x  = (const float*)d_in[0];
    const float* w  = (const float*)d_in[1];
    const float* ap = (const float*)d_in[2];
    const float* an = (const float*)d_in[3];
    const float* bs = (const float*)d_in[4];
    float* out = (float*)d_out;

    const int N = in_sizes[2];            // 4096
    const int K = in_sizes[1] / N;        // 4096
    const int M = in_sizes[0] / K;        // 8192

    const bool ok4 = (M % 256 == 0) && (N % 128 == 0) && (K % 512 == 0);
    const int Kb = K / 2;                 // packed fp4 bytes per row
    const size_t needA4 = (size_t)M * Kb;
    const size_t needB4 = (size_t)N * Kb;

    if (ok4 && ws_size >= needA4 + needB4) {
        unsigned char* aq = (unsigned char*)d_ws;
        unsigned char* wq = (unsigned char*)d_ws + needA4;
        const int ABLK = 2048, WBLK = 1024;
        quant_ab4_kernel<<<ABLK + WBLK, 256, 0, stream>>>(
            x, w, ap, an, aq, wq, K, (long)M * K, (long)N * K, ABLK);
        dim3 grid(N / 128, M / 256);
        gemm4p<<<grid, 512, 0, stream>>>(aq, wq, bs, out, M, N, Kb);
    } else if (ws_size >= (size_t)(M + N) * K * 2) {
        unsigned short* aq = (unsigned short*)d_ws;
        unsigned short* wq = (unsigned short*)((char*)d_ws + (size_t)M * K * 2);
        quant_a_kernel<<<2048, 256, 0, stream>>>(x, aq, (long)M * K);
        quant_w_kernel<<<2048, 256, 0, stream>>>(w, ap, an, wq, K, (long)N * K);
        dim3 grid(N / 128, M / 128);
        gemm_tern<0><<<grid, 256, 0, stream>>>(aq, wq, nullptr, nullptr,
                                               ap, an, bs, out, M, N, K);
    } else {
        dim3 grid(N / 128, M / 128);
        gemm_tern<1><<<grid, 256, 0, stream>>>(nullptr, nullptr, x, w,
                                               ap, an, bs, out, M, N, K);
    }
}

// Round 24
// 147.272 us; speedup vs baseline: 1.0654x; 1.0654x over previous
//
#include <hip/hip_runtime.h>
#include <hip/hip_bf16.h>

#define DELTA 0.05f

typedef __attribute__((ext_vector_type(8))) short short8;
typedef __attribute__((ext_vector_type(4))) float f32x4;
typedef __attribute__((ext_vector_type(4))) int int4v;
typedef __attribute__((ext_vector_type(8))) int int8v;
typedef __attribute__((ext_vector_type(16))) float f32x16;

__device__ __forceinline__ unsigned short tern_bits(float v) {
    return v > DELTA ? 0x3F80u : (v < -DELTA ? 0xBF80u : 0u);
}

__device__ __forceinline__ short f32_to_bf16_bits(float v) {
    __hip_bfloat16 h = __float2bfloat16(v);
    unsigned short bits;
    __builtin_memcpy(&bits, &h, 2);
    return (short)bits;
}

// e2m1 nibble: nearest of {0,±0.5,±1,±1.5,±2,±3,±4,±6}; exact for {0,±1}
__device__ __forceinline__ unsigned int nib_e2m1(float v) {
    float a = fabsf(v);
    unsigned int s = v < 0.0f ? 8u : 0u;
    unsigned int m;
    if (a < 0.25f) return 0u;
    else if (a < 0.75f) m = 1u;
    else if (a < 1.25f) m = 2u;
    else if (a < 1.75f) m = 3u;
    else if (a < 2.5f)  m = 4u;
    else if (a < 3.5f)  m = 5u;
    else if (a < 5.0f)  m = 6u;
    else                m = 7u;
    return s | m;
}

// ---- fused quantize to PACKED fp4 (2 elems/byte; layout verified r20) ------
// r24 change: W-side nibble codes hoisted PER ROW (ev only ever in
// {pv, nv, 0} -> np/nn computed once, per-element work = 2-compare select,
// same cost as the x-side). Semantically identical to r22/r23.
__global__ void quant_ab4_kernel(const float* __restrict__ x,
                                 const float* __restrict__ w,
                                 const float* __restrict__ ap,
                                 const float* __restrict__ an,
                                 unsigned char* __restrict__ aq,
                                 unsigned char* __restrict__ wq,
                                 int K, long totalA, long totalW, int ABLK) {
    if ((int)blockIdx.x < ABLK) {
        long idx = ((long)blockIdx.x * blockDim.x + threadIdx.x) * 32;
        long stride = (long)ABLK * blockDim.x * 32;
        for (; idx < totalA; idx += stride) {
            const float4* p = reinterpret_cast<const float4*>(x + idx);
            union { unsigned char c[16]; int4v v; } r;
#pragma unroll
            for (int q = 0; q < 8; ++q) {
                float4 f = p[q];
                unsigned int lo0 = f.x > DELTA ? 2u : (f.x < -DELTA ? 10u : 0u);
                unsigned int hi0 = f.y > DELTA ? 2u : (f.y < -DELTA ? 10u : 0u);
                unsigned int lo1 = f.z > DELTA ? 2u : (f.z < -DELTA ? 10u : 0u);
                unsigned int hi1 = f.w > DELTA ? 2u : (f.w < -DELTA ? 10u : 0u);
                r.c[q * 2 + 0] = (unsigned char)(lo0 | (hi0 << 4));
                r.c[q * 2 + 1] = (unsigned char)(lo1 | (hi1 << 4));
            }
            *reinterpret_cast<int4v*>(aq + idx / 2) = r.v;
        }
    } else {
        int wb = (int)blockIdx.x - ABLK;
        int nwb = (int)gridDim.x - ABLK;
        long idx = ((long)wb * blockDim.x + threadIdx.x) * 32;
        long stride = (long)nwb * blockDim.x * 32;
        for (; idx < totalW; idx += stride) {
            int n = (int)(idx / K);
            // per-row nibble codes (hoisted): ev is only ever pv, nv, or 0
            unsigned int np = nib_e2m1(ap[n]);
            unsigned int nn = nib_e2m1(-an[n]);
            const float4* p = reinterpret_cast<const float4*>(w + idx);
            union { unsigned char c[16]; int4v v; } r;
#pragma unroll
            for (int q = 0; q < 8; ++q) {
                float4 f = p[q];
                unsigned int n0 = f.x > DELTA ? np : (f.x < -DELTA ? nn : 0u);
                unsigned int n1 = f.y > DELTA ? np : (f.y < -DELTA ? nn : 0u);
                unsigned int n2 = f.z > DELTA ? np : (f.z < -DELTA ? nn : 0u);
                unsigned int n3 = f.w > DELTA ? np : (f.w < -DELTA ? nn : 0u);
                r.c[q * 2 + 0] = (unsigned char)(n0 | (n1 << 4));
                r.c[q * 2 + 1] = (unsigned char)(n2 | (n3 << 4));
            }
            *reinterpret_cast<int4v*>(wq + idx / 2) = r.v;
        }
    }
}

// ====== 256x128 fp4 GEMM (r22/r23 keeper, byte-identical) ====================
// GEMM verified stable at ~103.5us across r22/r23 builds (absmax 0).
__global__ __attribute__((amdgpu_flat_work_group_size(512, 512),
                          amdgpu_waves_per_eu(2, 2))) void gemm4p(
    const unsigned char* __restrict__ A, const unsigned char* __restrict__ B,
    const float* __restrict__ bias, float* __restrict__ C,
    int M, int N, int Kb) {
    __shared__ unsigned char As[2 * 256 * 128];   // 64 KB (2 buf x 32KB)
    __shared__ unsigned char Bs[2 * 128 * 128];   // 32 KB (2 buf x 16KB)

    const int tid = threadIdx.x;
    const int wid = tid >> 6;
    const int ln  = tid & 63;
    const int wr  = wid >> 2;   // 0..1 (128-row half)
    const int wc  = wid & 3;    // 0..3 (32-col group)

    // --- XCD-chunked swizzle (bijective: gridDim.y % 8 == 0)
    int bx = blockIdx.x, by = blockIdx.y;
    if ((gridDim.y & 7) == 0) {
        const int nbx = gridDim.x;
        const int rpx = gridDim.y >> 3;
        int bid = by * nbx + bx;
        int xcd = bid & 7;
        int off = bid >> 3;
        by = xcd * rpx + (off % rpx);
        bx = off / rpx;
    }
    const int brow = by * 256;
    const int bcol = bx * 128;

    const int NT   = Kb >> 7;   // 128-byte K-tiles (256 fp4 elems)
    const int STOT = NT * 3;    // units per tile: {B, A.h0, A.h1}, 16KB each

    const int srow   = ln >> 3;
    const int scol   = ((ln & 7) ^ srow) * 16;  // inverse-swizzled source byte
    const int chunk0 = wid * 2;

    const int ln31 = ln & 31;
    const int swz  = (ln & 7) << 4;
    const int koff = (ln >> 5) << 4;

    f32x16 acc[4] = {};
    int8v bfrag[4];
    int s = 0;

    auto STAGE = [&](int si) {
        if (si >= STOT) return;
        int tile = si / 3, kind = si - tile * 3, buf = tile & 1;
        int kt = tile << 7;
        const unsigned char* g;
        int grow;
        unsigned char* lb;
        if (kind == 0) { g = B; grow = bcol; lb = Bs + buf * 16384; }
        else {
            g = A; grow = brow + (kind - 1) * 128;
            lb = As + buf * 32768 + (kind - 1) * 16384;
        }
#pragma unroll
        for (int j = 0; j < 2; ++j) {
            int c = chunk0 + j;
            const unsigned char* src =
                g + (size_t)(grow + c * 8 + srow) * Kb + kt + scol;
            __builtin_amdgcn_global_load_lds(
                (const __attribute__((address_space(1))) void*)src,
                (__attribute__((address_space(3))) void*)(lb + c * 1024),
                16, 0, 0);
        }
    };

#define PHASE(BUF, Q, FIRST, DOSTG, TAIL)                                      \
    {                                                                          \
        const char* Ab = (const char*)As + (BUF) * 32768;                      \
        const char* Bb = (const char*)Bs + (BUF) * 16384;                      \
        int8v afrag[4];                                                        \
        {                                                                      \
            int r = wr * 128 + (Q) * 32 + ln31;                                \
            _Pragma("unroll")                                                  \
            for (int ks = 0; ks < 4; ++ks) {                                   \
                int4v t = *(const int4v*)(Ab + r * 128 +                       \
                                          ((ks * 32 + koff) ^ swz));           \
                afrag[ks] = (int8v){t[0], t[1], t[2], t[3], 0, 0, 0, 0};       \
            }                                                                  \
        }                                                                      \
        if (FIRST) {                                                           \
            int r = wc * 32 + ln31;                                            \
            _Pragma("unroll")                                                  \
            for (int ks = 0; ks < 4; ++ks) {                                   \
                int4v t = *(const int4v*)(Bb + r * 128 +                       \
                                          ((ks * 32 + koff) ^ swz));           \
                bfrag[ks] = (int8v){t[0], t[1], t[2], t[3], 0, 0, 0, 0};       \
            }                                                                  \
        }                                                                      \
        if (DOSTG) { STAGE(s); ++s; }                                          \
        __builtin_amdgcn_s_barrier();                                          \
        __builtin_amdgcn_s_setprio(1);                                         \
        _Pragma("unroll")                                                      \
        for (int ks = 0; ks < 4; ++ks)                                         \
            acc[(Q)] = __builtin_amdgcn_mfma_scale_f32_32x32x64_f8f6f4(        \
                afrag[ks], bfrag[ks], acc[(Q)],                                \
                4, 4, 0, 0x7F7F7F7F, 0, 0x7F7F7F7F);                           \
        __builtin_amdgcn_s_setprio(0);                                         \
        TAIL;                                                                  \
    }
#define GATE4 asm volatile("s_waitcnt vmcnt(4)" ::: "memory"); __builtin_amdgcn_s_barrier()
#define GATE0 asm volatile("s_waitcnt vmcnt(0)" ::: "memory"); __builtin_amdgcn_s_barrier()

    // prologue: T0{B,A0,A1} + T1{B,A0}; gate T0 (T1's 4 loads in flight)
    for (int i = 0; i < 5; ++i) { STAGE(s); ++s; }
    asm volatile("s_waitcnt vmcnt(4)" ::: "memory");
    __builtin_amdgcn_s_barrier();

    const int NI = (NT - 2) >> 1;
#pragma unroll 1
    for (int p = 0; p < NI; ++p) {
        PHASE(0, 0, true,  true,  (void)0)   // stage T+1.A1
        PHASE(0, 1, false, true,  (void)0)   // stage T+2.B (buf0.B read ph1 only)
        PHASE(0, 2, false, false, (void)0)
        PHASE(0, 3, false, true,  GATE4)     // stage T+2.A0 after A0's last reads
        PHASE(1, 0, true,  true,  (void)0)   // stage T+2.A1 (fenced by ph4 gate)
        PHASE(1, 1, false, true,  (void)0)   // stage T+3.B
        PHASE(1, 2, false, false, (void)0)
        PHASE(1, 3, false, true,  GATE4)     // stage T+3.A0
    }
    // epilogue: tiles NT-2 (buf0), NT-1 (buf1); one unit left (T_{NT-1}.A1)
    PHASE(0, 0, true,  true,  (void)0)
    PHASE(0, 1, false, false, (void)0)
    PHASE(0, 2, false, false, (void)0)
    PHASE(0, 3, false, false, GATE0)
    PHASE(1, 0, true,  false, (void)0)
    PHASE(1, 1, false, false, (void)0)
    PHASE(1, 2, false, false, (void)0)
    PHASE(1, 3, false, false, (void)0)
#undef PHASE
#undef GATE4
#undef GATE0

    // C write + bias. 32x32 D layout: col=lane&31, row=(q&3)+8*(q>>2)+4*(ln>>5)
#pragma unroll
    for (int Q = 0; Q < 4; ++Q) {
        int col = bcol + wc * 32 + ln31;
        float bv = bias[col];
        int rowbase = brow + wr * 128 + Q * 32 + ((ln >> 5) << 2);
#pragma unroll
        for (int q = 0; q < 16; ++q) {
            int row = rowbase + (q & 3) + ((q >> 2) << 3);
            C[(size_t)row * N + col] = acc[Q][q] + bv;
        }
    }
}

// ---------------- bf16 quant + fallback 128^2 GEMM (round-1, known-good) ----
__global__ void quant_a_kernel(const float* __restrict__ x,
                               unsigned short* __restrict__ out, long total) {
    long idx = ((long)blockIdx.x * blockDim.x + threadIdx.x) * 8;
    long stride = (long)gridDim.x * blockDim.x * 8;
    for (; idx < total; idx += stride) {
        const float4* p = reinterpret_cast<const float4*>(x + idx);
        float4 v0 = p[0], v1 = p[1];
        short8 r;
        r[0] = (short)tern_bits(v0.x); r[1] = (short)tern_bits(v0.y);
        r[2] = (short)tern_bits(v0.z); r[3] = (short)tern_bits(v0.w);
        r[4] = (short)tern_bits(v1.x); r[5] = (short)tern_bits(v1.y);
        r[6] = (short)tern_bits(v1.z); r[7] = (short)tern_bits(v1.w);
        *reinterpret_cast<short8*>(out + idx) = r;
    }
}

__global__ void quant_w_kernel(const float* __restrict__ w,
                               const float* __restrict__ ap,
                               const float* __restrict__ an,
                               unsigned short* __restrict__ out,
                               int K, long total) {
    long idx = ((long)blockIdx.x * blockDim.x + threadIdx.x) * 8;
    long stride = (long)gridDim.x * blockDim.x * 8;
    for (; idx < total; idx += stride) {
        int n = (int)(idx / K);
        float pv = ap[n], nv = -an[n];
        const float4* p = reinterpret_cast<const float4*>(w + idx);
        float4 v0 = p[0], v1 = p[1];
        float vals[8] = {v0.x, v0.y, v0.z, v0.w, v1.x, v1.y, v1.z, v1.w};
        short8 r;
#pragma unroll
        for (int e = 0; e < 8; ++e) {
            float v = vals[e];
            float ev = v > DELTA ? pv : (v < -DELTA ? nv : 0.0f);
            r[e] = f32_to_bf16_bits(ev);
        }
        *reinterpret_cast<short8*>(out + idx) = r;
    }
}

template <int MODE>
__global__ __launch_bounds__(256) void gemm_tern(
    const unsigned short* __restrict__ A, const unsigned short* __restrict__ B,
    const float* __restrict__ Xf, const float* __restrict__ Wf,
    const float* __restrict__ alpha_p, const float* __restrict__ alpha_n,
    const float* __restrict__ bias, float* __restrict__ C,
    int M, int N, int K) {
    __shared__ unsigned short As[128 * 32];
    __shared__ unsigned short Bs[128 * 32];

    const int tid = threadIdx.x;
    const int wv = tid >> 6;
    const int ln = tid & 63;
    const int brow = blockIdx.y * 128;
    const int bcol = blockIdx.x * 128;
    const int wr = wv >> 1;
    const int wc = wv & 1;

    f32x4 acc[4][4] = {};

    for (int kt = 0; kt < K; kt += 32) {
        if (MODE == 0) {
#pragma unroll
            for (int j = 0; j < 2; ++j) {
                int chunk = wv * 2 + j;
                int r = chunk * 16 + (ln >> 2);
                int kc = (ln & 3) * 8;
                const unsigned short* ga = A + (size_t)(brow + r) * K + kt + kc;
                const unsigned short* gb = B + (size_t)(bcol + r) * K + kt + kc;
                __builtin_amdgcn_global_load_lds(
                    (const __attribute__((address_space(1))) void*)ga,
                    (__attribute__((address_space(3))) void*)(As + chunk * 512),
                    16, 0, 0);
                __builtin_amdgcn_global_load_lds(
                    (const __attribute__((address_space(1))) void*)gb,
                    (__attribute__((address_space(3))) void*)(Bs + chunk * 512),
                    16, 0, 0);
            }
        } else {
#pragma unroll
            for (int j = 0; j < 2; ++j) {
                int chunk = wv * 2 + j;
                int r = chunk * 16 + (ln >> 2);
                int kc = (ln & 3) * 8;
                const float4* xa =
                    reinterpret_cast<const float4*>(Xf + (size_t)(brow + r) * K + kt + kc);
                float4 a0 = xa[0], a1 = xa[1];
                short8 ta;
                ta[0] = (short)tern_bits(a0.x); ta[1] = (short)tern_bits(a0.y);
                ta[2] = (short)tern_bits(a0.z); ta[3] = (short)tern_bits(a0.w);
                ta[4] = (short)tern_bits(a1.x); ta[5] = (short)tern_bits(a1.y);
                ta[6] = (short)tern_bits(a1.z); ta[7] = (short)tern_bits(a1.w);
                *reinterpret_cast<short8*>(As + chunk * 512 + ln * 8) = ta;

                int rn = bcol + r;
                float pv = alpha_p[rn], nv = -alpha_n[rn];
                const float4* wb =
                    reinterpret_cast<const float4*>(Wf + (size_t)rn * K + kt + kc);
                float4 b0 = wb[0], b1 = wb[1];
                float vals[8] = {b0.x, b0.y, b0.z, b0.w, b1.x, b1.y, b1.z, b1.w};
                short8 tb;
#pragma unroll
                for (int e = 0; e < 8; ++e) {
                    float v = vals[e];
                    float ev = v > DELTA ? pv : (v < -DELTA ? nv : 0.0f);
                    tb[e] = f32_to_bf16_bits(ev);
                }
                *reinterpret_cast<short8*>(Bs + chunk * 512 + ln * 8) = tb;
            }
        }
        __syncthreads();

        short8 af[4], bfr[4];
#pragma unroll
        for (int i = 0; i < 4; ++i) {
            int ra = wr * 64 + i * 16 + (ln & 15);
            af[i] = *reinterpret_cast<const short8*>(As + ra * 32 + (ln >> 4) * 8);
            int rb = wc * 64 + i * 16 + (ln & 15);
            bfr[i] = *reinterpret_cast<const short8*>(Bs + rb * 32 + (ln >> 4) * 8);
        }
#pragma unroll
        for (int i = 0; i < 4; ++i)
#pragma unroll
            for (int j = 0; j < 4; ++j)
                acc[i][j] = __builtin_amdgcn_mfma_f32_16x16x32_bf16(
                    af[i], bfr[j], acc[i][j], 0, 0, 0);
        __syncthreads();
    }

#pragma unroll
    for (int j = 0; j < 4; ++j) {
        int col = bcol + wc * 64 + j * 16 + (ln & 15);
        float bv = bias[col];
#pragma unroll
        for (int i = 0; i < 4; ++i) {
            int row0 = brow + wr * 64 + i * 16 + (ln >> 4) * 4;
#pragma unroll
            for (int q = 0; q < 4; ++q) {
                C[(size_t)(row0 + q) * N + col] = acc[i][j][q] + bv;
            }
        }
    }
}

extern "C" void kernel_launch(void* const* d_in, const int* in_sizes, int n_in,
                              void* d_out, int out_size, void* d_ws, size_t ws_size,
                              hipStream_t stream) {
    const float* x  = (const float*)d_in[0];
    const float* w  = (const float*)d_in[1];
    const float* ap = (const float*)d_in[2];
    const float* an = (const float*)d_in[3];
    const float* bs = (const float*)d_in[4];
    float* out = (float*)d_out;

    const int N = in_sizes[2];            // 4096
    const int K = in_sizes[1] / N;        // 4096
    const int M = in_sizes[0] / K;        // 8192

    const bool ok4 = (M % 256 == 0) && (N % 128 == 0) && (K % 512 == 0);
    const int Kb = K / 2;                 // packed fp4 bytes per row
    const size_t needA4 = (size_t)M * Kb;
    const size_t needB4 = (size_t)N * Kb;

    if (ok4 && ws_size >= needA4 + needB4) {
        unsigned char* aq = (unsigned char*)d_ws;
        unsigned char* wq = (unsigned char*)d_ws + needA4;
        const int ABLK = 2048, WBLK = 1024;
        quant_ab4_kernel<<<ABLK + WBLK, 256, 0, stream>>>(
            x, w, ap, an, aq, wq, K, (long)M * K, (long)N * K, ABLK);
        dim3 grid(N / 128, M / 256);
        gemm4p<<<grid, 512, 0, stream>>>(aq, wq, bs, out, M, N, Kb);
    } else if (ws_size >= (size_t)(M + N) * K * 2) {
        unsigned short* aq = (unsigned short*)d_ws;
        unsigned short* wq = (unsigned short*)((char*)d_ws + (size_t)M * K * 2);
        quant_a_kernel<<<2048, 256, 0, stream>>>(x, aq, (long)M * K);
        quant_w_kernel<<<2048, 256, 0, stream>>>(w, ap, an, wq, K, (long)N * K);
        dim3 grid(N / 128, M / 128);
        gemm_tern<0><<<grid, 256, 0, stream>>>(aq, wq, nullptr, nullptr,
                                               ap, an, bs, out, M, N, K);
    } else {
        dim3 grid(N / 128, M / 128);
        gemm_tern<1><<<grid, 256, 0, stream>>>(nullptr, nullptr, x, w,
                                               ap, an, bs, out, M, N, K);
    }
}